// Round 1
// 1112.842 us; speedup vs baseline: 1.0029x; 1.0029x over previous
//
#include <hip/hip_runtime.h>

#define GRID_NN 128
#define NV (GRID_NN * GRID_NN)   // 16384
#define BATCH 8
#define NDIM 3
#define NBLK 256                 // one block per CU
#define TPB 64                   // one wave per block

// Batch-stationary: one thread per vertex. Reads the 7 banded L weights ONCE
// (vs 8x in the previous version), then processes all 8 batches x 3 dims with
// x (1.57 MB total) served from L1/L2. Deterministic two-stage reduction via
// workspace; no atomics, no pre-zero kernel.
__global__ __launch_bounds__(TPB) void lap_band_kernel(const float* __restrict__ L,
                                                       const float* __restrict__ x,
                                                       float* __restrict__ partials) {
    const int i = blockIdx.x * TPB + threadIdx.x;   // vertex id, exact cover of NV

    // nonzeros of row i only at columns i + {-128,-127,-1,0,1,127,128};
    // values READ from dense L (robust to normalization & boundary structure:
    // wrap-around columns are structural zeros in L and contribute nothing).
    const int offs[7] = {-GRID_NN, -GRID_NN + 1, -1, 0, 1, GRID_NN - 1, GRID_NN};

    float w[7];
    int   jn[7];
    const size_t rowbase = (size_t)i * NV;
#pragma unroll
    for (int k = 0; k < 7; ++k) {
        int j = i + offs[k];
        bool valid = (j >= 0) && (j < NV);
        jn[k] = valid ? j : i;                 // safe index; weight forced to 0
        w[k]  = valid ? __builtin_nontemporal_load(&L[rowbase + j]) : 0.0f;
    }

    float acc[BATCH];
#pragma unroll
    for (int b = 0; b < BATCH; ++b) {
        const float* __restrict__ xb = x + (size_t)b * (NV * NDIM);
        float y0 = 0.0f, y1 = 0.0f, y2 = 0.0f;
#pragma unroll
        for (int k = 0; k < 7; ++k) {
            const float* xj = xb + (size_t)jn[k] * NDIM;
            float wk = w[k];
            y0 += wk * xj[0];
            y1 += wk * xj[1];
            y2 += wk * xj[2];
        }
        acc[b] = y0 * y0 + y1 * y1 + y2 * y2;
    }

    // wave-64 shuffle reduction for each batch (single wave per block)
#pragma unroll
    for (int b = 0; b < BATCH; ++b) {
#pragma unroll
        for (int s = 32; s > 0; s >>= 1) acc[b] += __shfl_down(acc[b], s, 64);
    }

    if (threadIdx.x == 0) {
#pragma unroll
        for (int b = 0; b < BATCH; ++b)
            partials[(size_t)blockIdx.x * BATCH + b] = acc[b];
    }
}

__global__ __launch_bounds__(256) void lap_reduce_kernel(const float* __restrict__ partials,
                                                         float* __restrict__ out) {
    const int t = threadIdx.x;          // 256 threads, one per partial set
    float acc[BATCH];
#pragma unroll
    for (int b = 0; b < BATCH; ++b) acc[b] = partials[(size_t)t * BATCH + b];

#pragma unroll
    for (int b = 0; b < BATCH; ++b) {
#pragma unroll
        for (int s = 32; s > 0; s >>= 1) acc[b] += __shfl_down(acc[b], s, 64);
    }

    __shared__ float lds[4][BATCH];
    const int lane = t & 63;
    const int wid  = t >> 6;
    if (lane == 0) {
#pragma unroll
        for (int b = 0; b < BATCH; ++b) lds[wid][b] = acc[b];
    }
    __syncthreads();
    if (t < BATCH) {
        float s = lds[0][t] + lds[1][t] + lds[2][t] + lds[3][t];
        out[t] = s * (1.0f / (float)(NV * NDIM));
    }
}

extern "C" void kernel_launch(void* const* d_in, const int* in_sizes, int n_in,
                              void* d_out, int out_size, void* d_ws, size_t ws_size,
                              hipStream_t stream) {
    const float* L = (const float*)d_in[0];   // [NV, NV] fp32
    const float* x = (const float*)d_in[1];   // [BATCH, NV, 3] fp32
    float* out = (float*)d_out;               // [BATCH] fp32
    float* partials = (float*)d_ws;           // [NBLK, BATCH] = 8 KB

    lap_band_kernel<<<NBLK, TPB, 0, stream>>>(L, x, partials);
    lap_reduce_kernel<<<1, 256, 0, stream>>>(partials, out);
}